// Round 1
// baseline (541.715 us; speedup 1.0000x reference)
//
#include <hip/hip_runtime.h>
#include <hip/hip_fp16.h>
#include <stdint.h>

#define S_DIM 64
#define L_DIM 64
#define B_DIM 16
#define LB    1024      // L*B
#define DIN   1024
#define DA    512
#define M_TOT 65536     // S*LB

#define BM 256
#define BN 256
#define BK 64
#define NT (DIN / BK)   // 16 K-tiles

using f16x8 = __attribute__((ext_vector_type(8))) _Float16;
using f32x4 = __attribute__((ext_vector_type(4))) float;

typedef const __attribute__((address_space(1))) void* gas_ptr;
typedef __attribute__((address_space(3))) void* las_ptr;

__device__ __forceinline__ void load_lds16(const void* g, void* l) {
    __builtin_amdgcn_global_load_lds((gas_ptr)g, (las_ptr)l, 16, 0, 0);
}

__device__ __forceinline__ float fast_tanh(float x) {
    return 1.0f - 2.0f / (__expf(2.0f * x) + 1.0f);
}

// ---------------- K0a: convert Wc, Wq, query to fp16 in workspace ----------
__global__ void cvt_all(const float* __restrict__ Wc, const float* __restrict__ Wq,
                        const float* __restrict__ q,
                        _Float16* __restrict__ Wch, _Float16* __restrict__ Wqh,
                        _Float16* __restrict__ Qh) {
    int i = blockIdx.x * 256 + threadIdx.x;
    if (i < DA * DIN)            Wch[i] = (_Float16)Wc[i];
    else if (i < 2 * DA * DIN)   Wqh[i - DA * DIN] = (_Float16)Wq[i - DA * DIN];
    else                         Qh[i - 2 * DA * DIN] = (_Float16)q[i - 2 * DA * DIN];
}

// ---------------- K0c: convert context to fp16 (streaming, BW-bound) -------
__global__ __launch_bounds__(256) void ctx_cvt(const float* __restrict__ src,
                                               _Float16* __restrict__ dst) {
    const size_t nchunk = (size_t)M_TOT * DIN / 8;   // 8M f16x8 chunks
    size_t stride = (size_t)gridDim.x * 256;
    for (size_t c = (size_t)blockIdx.x * 256 + threadIdx.x; c < nchunk; c += stride) {
        f32x4 a = *(const f32x4*)(src + c * 8);
        f32x4 b = *(const f32x4*)(src + c * 8 + 4);
        f16x8 h = {(_Float16)a[0], (_Float16)a[1], (_Float16)a[2], (_Float16)a[3],
                   (_Float16)b[0], (_Float16)b[1], (_Float16)b[2], (_Float16)b[3]};
        *(f16x8*)(dst + c * 8) = h;
    }
}

// ---------------- K0b: qp'[lb][n] = query@Wq^T + bq + bc -------------------
__global__ __launch_bounds__(256) void qp_gemm(
    const _Float16* __restrict__ Qh,    // [LB][DIN]
    const _Float16* __restrict__ Wqh,   // [DA][DIN]
    const float* __restrict__ bq, const float* __restrict__ bc,
    float* __restrict__ qp)             // [LB][DA]
{
    __shared__ __align__(16) _Float16 lA[64 * 64];
    __shared__ __align__(16) _Float16 lB[64 * 64];
    const int t = threadIdx.x;
    const int w = t >> 6, lane = t & 63;
    const int quad = lane >> 4, m16 = lane & 15;
    const int n0 = blockIdx.x * 64, lb0 = blockIdx.y * 64;

    f32x4 acc[4] = {};

    for (int kt = 0; kt < DIN / 64; ++kt) {
#pragma unroll
        for (int i = 0; i < 2; ++i) {
            int c = (w * 2 + i) * 64 + lane;
            int row = c >> 3;
            int kc = (c & 7) ^ (row & 7);
            load_lds16(Qh  + (size_t)(lb0 + row) * DIN + kt * 64 + kc * 8, (char*)lA + (size_t)c * 16);
            load_lds16(Wqh + (size_t)(n0  + row) * DIN + kt * 64 + kc * 8, (char*)lB + (size_t)c * 16);
        }
        __syncthreads();
#pragma unroll
        for (int kk = 0; kk < 64; kk += 32) {
            int cq = (kk >> 3) + quad;
            int ar = 16 * w + m16;
            f16x8 a = *(const f16x8*)((const char*)lA + ar * 128 + ((cq ^ (ar & 7)) * 16));
#pragma unroll
            for (int j = 0; j < 4; ++j) {
                int br = 16 * j + m16;
                f16x8 b = *(const f16x8*)((const char*)lB + br * 128 + ((cq ^ (br & 7)) * 16));
                acc[j] = __builtin_amdgcn_mfma_f32_16x16x32_f16(a, b, acc[j], 0, 0, 0);
            }
        }
        __syncthreads();
    }
#pragma unroll
    for (int j = 0; j < 4; ++j) {
        int n = n0 + 16 * j + m16;
        float bias = bq[n] + bc[n];
#pragma unroll
        for (int r = 0; r < 4; ++r) {
            int lb = lb0 + 16 * w + quad * 4 + r;
            qp[(size_t)lb * DA + n] = acc[j][r] + bias;
        }
    }
}

// ---------------- K1: 256x256 8-wave dbuf phase-split score GEMM -----------
// acc initialized from qp (C-init), partials to sc[nq][m] (no atomics).
__global__ __launch_bounds__(512, 2) void score_gemm3(
    const _Float16* __restrict__ ctxh,  // [M_TOT][DIN] fp16
    const _Float16* __restrict__ Wch,   // [DA][DIN]
    const float* __restrict__ qp,       // [LB][DA]
    const float* __restrict__ v,        // [DA]
    float* __restrict__ sc)             // [2][M_TOT] partials per n-block
{
    __shared__ __align__(16) _Float16 lds[2][2][BM * BK];  // [buf][A=0/B=1], 128 KB
    __shared__ float lP[4][BM];                             // 4 KB

    const int t = threadIdx.x;
    const int w = t >> 6, lane = t & 63;
    const int quad = lane >> 4, m16 = lane & 15;
    const int wm = w & 1, wn = w >> 1;          // 2 M-halves x 4 N-quarters

    // XCD-aware bijective swizzle (512 blocks, 512 % 8 == 0)
    int bid = blockIdx.x;
    int swz = (bid & 7) * 64 + (bid >> 3);
    const int nq = swz & 1;
    const int mb = swz >> 1;
    const int m0 = mb * BM;
    const int n0 = nq * BN;
    const int lb0 = m0 & (LB - 1);

    // staging: 2048 16B-chunks per matrix; chunk c = (w*4+i)*64 + lane
    // (wave-uniform LDS base + lane*16, pre-swizzled global source)
    auto stage = [&](int kt, int buf) {
#pragma unroll
        for (int i = 0; i < 4; ++i) {
            int c = (w * 4 + i) * 64 + lane;
            int row = c >> 3;                     // 0..255
            int kc = (c & 7) ^ (row & 7);         // swizzled source chunk
            load_lds16(ctxh + (size_t)(m0 + row) * DIN + kt * BK + kc * 8,
                       (char*)lds[buf][0] + (size_t)c * 16);
            load_lds16(Wch  + (size_t)(n0 + row) * DIN + kt * BK + kc * 8,
                       (char*)lds[buf][1] + (size_t)c * 16);
        }
    };

    // prologue: issue tile 0, overlap the qp C-init loads under the DMA
    stage(0, 0);

    f32x4 acc[8][4];
#pragma unroll
    for (int i = 0; i < 8; ++i) {
        int rl = wm * 128 + 16 * i + quad * 4;
#pragma unroll
        for (int j = 0; j < 4; ++j) {
            int n = n0 + wn * 64 + 16 * j + m16;
#pragma unroll
            for (int r = 0; r < 4; ++r)
                acc[i][j][r] = qp[(size_t)(lb0 + rl + r) * DA + n];
        }
    }

    asm volatile("s_waitcnt vmcnt(0)" ::: "memory");
    __builtin_amdgcn_s_barrier();
    __builtin_amdgcn_sched_barrier(0);

    for (int kt = 0; kt < NT; ++kt) {
        const int cur = kt & 1;
        if (kt + 1 < NT) stage(kt + 1, cur ^ 1);   // issue-early: full tile of slack
        const _Float16* lA = lds[cur][0];
        const _Float16* lB = lds[cur][1];

        // B fragments: read once per tile, held in regs across phases
        f16x8 b[2][4];
#pragma unroll
        for (int kk = 0; kk < 2; ++kk)
#pragma unroll
            for (int j = 0; j < 4; ++j) {
                int br = wn * 64 + 16 * j + m16;
                int cq = kk * 4 + quad;
                b[kk][j] = *(const f16x8*)((const char*)lB + br * 128 + ((cq ^ (br & 7)) * 16));
            }

#pragma unroll
        for (int p = 0; p < 4; ++p) {              // 4 phases x 16 MFMA
            f16x8 a[2][2];
#pragma unroll
            for (int ii = 0; ii < 2; ++ii) {
                int ar = wm * 128 + 16 * (2 * p + ii) + m16;
#pragma unroll
                for (int kk = 0; kk < 2; ++kk) {
                    int cq = kk * 4 + quad;
                    a[ii][kk] = *(const f16x8*)((const char*)lA + ar * 128 + ((cq ^ (ar & 7)) * 16));
                }
            }
            __builtin_amdgcn_s_barrier();          // raw: no vmcnt drain
            __builtin_amdgcn_s_setprio(1);
#pragma unroll
            for (int ii = 0; ii < 2; ++ii)
#pragma unroll
                for (int j = 0; j < 4; ++j)
#pragma unroll
                    for (int kk = 0; kk < 2; ++kk)
                        acc[2 * p + ii][j] = __builtin_amdgcn_mfma_f32_16x16x32_f16(
                            a[ii][kk], b[kk][j], acc[2 * p + ii][j], 0, 0, 0);
            __builtin_amdgcn_s_setprio(0);
        }

        asm volatile("s_waitcnt vmcnt(0)" ::: "memory");  // next tile landed
        __builtin_amdgcn_s_barrier();
        __builtin_amdgcn_sched_barrier(0);
    }

    // epilogue: tanh + v-dot (qp already folded into acc)
    float vv[4];
#pragma unroll
    for (int j = 0; j < 4; ++j) vv[j] = v[n0 + wn * 64 + 16 * j + m16];

    float part[32];
#pragma unroll
    for (int i = 0; i < 8; ++i)
#pragma unroll
        for (int r = 0; r < 4; ++r) {
            float s = 0.f;
#pragma unroll
            for (int j = 0; j < 4; ++j)
                s += fast_tanh(acc[i][j][r]) * vv[j];
            part[i * 4 + r] = s;
        }
#pragma unroll
    for (int off = 1; off < 16; off <<= 1) {
#pragma unroll
        for (int k = 0; k < 32; ++k) part[k] += __shfl_xor(part[k], off, 64);
    }
    if (m16 == 0) {
#pragma unroll
        for (int k = 0; k < 32; ++k) {
            int rl = wm * 128 + 16 * (k >> 2) + quad * 4 + (k & 3);
            lP[wn][rl] = part[k];
        }
    }
    __syncthreads();
    if (t < BM) {
        float s = lP[0][t] + lP[1][t] + lP[2][t] + lP[3][t];
        sc[(size_t)nq * M_TOT + m0 + t] = s;       // plain store, disjoint
    }
}

// ---------------- K1-B fallback: fp32-ctx score GEMM (atomic path) ---------
__global__ __launch_bounds__(256, 3) void score_gemm(
    const float* __restrict__ ctx, const _Float16* __restrict__ Wch,
    const float* __restrict__ qp, const float* __restrict__ v,
    float* __restrict__ scores)
{
    __shared__ __align__(16) _Float16 lA[128 * 64];
    __shared__ __align__(16) _Float16 lB[128 * 64];
    __shared__ float lP[2][128];

    const int t = threadIdx.x;
    const int w = t >> 6, lane = t & 63;
    const int quad = lane >> 4, m16 = lane & 15;
    const int wm = w & 1, wn = w >> 1;

    int bid = blockIdx.x;
    int xcd = bid & 7;
    int j2 = bid >> 3;
    int nqf = j2 & 3;
    int mbf = ((j2 >> 2) << 3) | xcd;
    const int m0 = mbf * 128;
    const int n0 = nqf * 128;

    f32x4 acc[4][4] = {};

    const int arow = t >> 1;
    const int akc4 = (t & 1) * 4;
    const float* gA = ctx + (size_t)(m0 + arow) * DIN + (t & 1) * 32;

    for (int kt = 0; kt < DIN / 64; ++kt) {
        {
            const float* p = gA + kt * 64;
            f32x4 f[8];
#pragma unroll
            for (int qd = 0; qd < 8; ++qd) f[qd] = *(const f32x4*)(p + qd * 4);
#pragma unroll
            for (int q2 = 0; q2 < 4; ++q2) {
                f16x8 h = {(_Float16)f[2*q2][0], (_Float16)f[2*q2][1],
                           (_Float16)f[2*q2][2], (_Float16)f[2*q2][3],
                           (_Float16)f[2*q2+1][0], (_Float16)f[2*q2+1][1],
                           (_Float16)f[2*q2+1][2], (_Float16)f[2*q2+1][3]};
                int c = akc4 + q2;
                *(f16x8*)((char*)lA + arow * 128 + ((c ^ (arow & 7)) * 16)) = h;
            }
        }
#pragma unroll
        for (int i = 0; i < 4; ++i) {
            int c = (w * 4 + i) * 64 + lane;
            int row = c >> 3;
            int kc = (c & 7) ^ (row & 7);
            load_lds16(Wch + (size_t)(n0 + row) * DIN + kt * 64 + kc * 8, (char*)lB + (size_t)c * 16);
        }
        __syncthreads();
#pragma unroll
        for (int kk = 0; kk < 64; kk += 32) {
            int cq = (kk >> 3) + quad;
            f16x8 a[4], b[4];
#pragma unroll
            for (int i = 0; i < 4; ++i) {
                int ar = wm * 64 + 16 * i + m16;
                a[i] = *(const f16x8*)((const char*)lA + ar * 128 + ((cq ^ (ar & 7)) * 16));
            }
#pragma unroll
            for (int j = 0; j < 4; ++j) {
                int br = wn * 64 + 16 * j + m16;
                b[j] = *(const f16x8*)((const char*)lB + br * 128 + ((cq ^ (br & 7)) * 16));
            }
#pragma unroll
            for (int i = 0; i < 4; ++i)
#pragma unroll
                for (int j = 0; j < 4; ++j)
                    acc[i][j] = __builtin_amdgcn_mfma_f32_16x16x32_f16(a[i], b[j], acc[i][j], 0, 0, 0);
        }
        __syncthreads();
    }

    float vv[4];
    int nn[4];
#pragma unroll
    for (int j = 0; j < 4; ++j) { nn[j] = n0 + wn * 64 + 16 * j + m16; vv[j] = v[nn[j]]; }

    float part[16];
#pragma unroll
    for (int i = 0; i < 4; ++i) {
#pragma unroll
        for (int r = 0; r < 4; ++r) {
            int gm = m0 + wm * 64 + 16 * i + quad * 4 + r;
            int lb = gm & (LB - 1);
            float s = 0.f;
#pragma unroll
            for (int j = 0; j < 4; ++j) {
                float x = acc[i][j][r] + qp[(size_t)lb * DA + nn[j]];
                s += fast_tanh(x) * vv[j];
            }
            part[i * 4 + r] = s;
        }
    }
#pragma unroll
    for (int off = 1; off < 16; off <<= 1) {
#pragma unroll
        for (int k = 0; k < 16; ++k) part[k] += __shfl_xor(part[k], off, 64);
    }
    if (m16 == 0) {
#pragma unroll
        for (int k = 0; k < 16; ++k) {
            int row_local = wm * 64 + 16 * (k >> 2) + quad * 4 + (k & 3);
            lP[wn][row_local] = part[k];
        }
    }
    __syncthreads();
    if (t < 128) {
        float s = lP[0][t] + lP[1][t];
        atomicAdd(&scores[m0 + t], s);
    }
}

// ---------------- K2: softmax over s — one wave per lb ---------------------
__global__ __launch_bounds__(64) void softmax3(const float* __restrict__ sc,
                                               const int* __restrict__ mask,
                                               float* __restrict__ alpha) {
    int lb = blockIdx.x;
    int s = threadIdx.x;
    int m = s * LB + lb;
    float x = sc[m] + sc[M_TOT + m];
    if (mask[m] == 0) x = -1e9f;
    float mx = x;
#pragma unroll
    for (int off = 1; off < 64; off <<= 1) mx = fmaxf(mx, __shfl_xor(mx, off, 64));
    float e = __expf(x - mx);
    float sum = e;
#pragma unroll
    for (int off = 1; off < 64; off <<= 1) sum += __shfl_xor(sum, off, 64);
    alpha[m] = e / sum;
}

__global__ __launch_bounds__(64) void softmax2(const float* __restrict__ scores,
                                               const int* __restrict__ mask,
                                               float* __restrict__ alpha) {
    int lb = blockIdx.x;
    int s = threadIdx.x;
    float x = scores[s * LB + lb];
    if (mask[s * LB + lb] == 0) x = -1e9f;
    float mx = x;
#pragma unroll
    for (int off = 1; off < 64; off <<= 1) mx = fmaxf(mx, __shfl_xor(mx, off, 64));
    float e = __expf(x - mx);
    float sum = e;
#pragma unroll
    for (int off = 1; off < 64; off <<= 1) sum += __shfl_xor(sum, off, 64);
    alpha[s * LB + lb] = e / sum;
}

// ---------------- K3-A: weighted sum from fp16 ctx_h -----------------------
__global__ __launch_bounds__(128) void weighted_sum2(
    const _Float16* __restrict__ ctxh, const float* __restrict__ alpha,
    float* __restrict__ out) {
    __shared__ float lAl[S_DIM];
    const int lb = blockIdx.x;
    const int t = threadIdx.x;
    if (t < S_DIM) lAl[t] = alpha[t * LB + lb];
    __syncthreads();
    float acc[8] = {};
    const _Float16* base = ctxh + (size_t)lb * DIN + t * 8;
#pragma unroll 8
    for (int s = 0; s < S_DIM; ++s) {
        float a = lAl[s];
        f16x8 c = *(const f16x8*)(base + (size_t)s * LB * DIN);
#pragma unroll
        for (int j = 0; j < 8; ++j) acc[j] += a * (float)c[j];
    }
    f32x4 lo = {acc[0], acc[1], acc[2], acc[3]};
    f32x4 hi = {acc[4], acc[5], acc[6], acc[7]};
    *(f32x4*)(out + (size_t)lb * DIN + t * 8) = lo;
    *(f32x4*)(out + (size_t)lb * DIN + t * 8 + 4) = hi;
}

// ---------------- K3-B fallback: weighted sum from fp32 ctx ----------------
__global__ __launch_bounds__(256) void weighted_sum(
    const float* __restrict__ ctx, const float* __restrict__ alpha,
    float* __restrict__ out) {
    __shared__ float lAl[S_DIM];
    const int lb = blockIdx.x;
    const int t = threadIdx.x;
    if (t < S_DIM) lAl[t] = alpha[t * LB + lb];
    __syncthreads();
    f32x4 acc = {0.f, 0.f, 0.f, 0.f};
    const float* base = ctx + (size_t)lb * DIN + t * 4;
#pragma unroll 4
    for (int s = 0; s < S_DIM; ++s) {
        float a = lAl[s];
        f32x4 c = *(const f32x4*)(base + (size_t)s * LB * DIN);
        acc += a * c;
    }
    *(f32x4*)(out + (size_t)lb * DIN + t * 4) = acc;
}

extern "C" void kernel_launch(void* const* d_in, const int* in_sizes, int n_in,
                              void* d_out, int out_size, void* d_ws, size_t ws_size,
                              hipStream_t stream) {
    (void)in_sizes; (void)n_in; (void)out_size;
    const float* ctx   = (const float*)d_in[0];
    const float* query = (const float*)d_in[1];
    const int*   mask  = (const int*)d_in[2];
    const float* Wc    = (const float*)d_in[3];
    const float* bc    = (const float*)d_in[4];
    const float* Wq    = (const float*)d_in[5];
    const float* bq    = (const float*)d_in[6];
    const float* v     = (const float*)d_in[7];

    float* out_attn  = (float*)d_out;                       // [LB][DIN]
    float* out_alpha = (float*)d_out + (size_t)LB * DIN;    // [S][LB]

    char* ws = (char*)d_ws;
    _Float16* Wch = (_Float16*)(ws);                        // 1 MB
    _Float16* Wqh = (_Float16*)(ws + (1 << 20));            // 1 MB
    _Float16* Qh  = (_Float16*)(ws + (2 << 20));            // 2 MB
    float*    qp  = (float*)(ws + (4 << 20));               // 2 MB
    float*    sc  = (float*)(ws + (6 << 20));               // 512 KB (2x partials)
    _Float16* ctxh = (_Float16*)(ws + (8 << 20));           // 128 MB

    const size_t need = (size_t)(8 + 128) << 20;
    const bool bigws = ws_size >= need;

    cvt_all<<<(2 * DA * DIN + LB * DIN) / 256, 256, 0, stream>>>(Wc, Wq, query, Wch, Wqh, Qh);
    qp_gemm<<<dim3(DA / 64, LB / 64), 256, 0, stream>>>(Qh, Wqh, bq, bc, qp);

    if (bigws) {
        ctx_cvt<<<8192, 256, 0, stream>>>(ctx, ctxh);
        score_gemm3<<<(M_TOT / BM) * (DA / BN), 512, 0, stream>>>(ctxh, Wch, qp, v, sc);
        softmax3<<<LB, 64, 0, stream>>>(sc, mask, out_alpha);
        weighted_sum2<<<LB, 128, 0, stream>>>(ctxh, out_alpha, out_attn);
    } else {
        hipMemsetAsync(sc, 0, (size_t)M_TOT * sizeof(float), stream);
        score_gemm<<<2048, 256, 0, stream>>>(ctx, Wch, qp, v, sc);
        softmax2<<<LB, 64, 0, stream>>>(sc, mask, out_alpha);
        weighted_sum<<<LB, 256, 0, stream>>>(ctx, out_alpha, out_attn);
    }
}

// Round 3
// 483.422 us; speedup vs baseline: 1.1206x; 1.1206x over previous
//
#include <hip/hip_runtime.h>
#include <hip/hip_fp16.h>
#include <stdint.h>

#define S_DIM 64
#define L_DIM 64
#define B_DIM 16
#define LB    1024      // L*B
#define DIN   1024
#define DA    512
#define M_TOT 65536     // S*LB

// fused score GEMM geometry: one block covers ALL of N (DA=512)
#define BM 128
#define BN 512
#define BK 64
#define NT (DIN / BK)   // 16 K-tiles

using f16x8 = __attribute__((ext_vector_type(8))) _Float16;
using f32x4 = __attribute__((ext_vector_type(4))) float;

typedef const __attribute__((address_space(1))) void* gas_ptr;
typedef __attribute__((address_space(3))) void* las_ptr;

__device__ __forceinline__ void load_lds16(const void* g, void* l) {
    __builtin_amdgcn_global_load_lds((gas_ptr)g, (las_ptr)l, 16, 0, 0);
}

__device__ __forceinline__ float fast_tanh(float x) {
    return 1.0f - 2.0f / (__expf(2.0f * x) + 1.0f);
}

// ---------------- K0a: convert Wc, Wq, query to fp16 in workspace ----------
__global__ void cvt_all(const float* __restrict__ Wc, const float* __restrict__ Wq,
                        const float* __restrict__ q,
                        _Float16* __restrict__ Wch, _Float16* __restrict__ Wqh,
                        _Float16* __restrict__ Qh) {
    int i = blockIdx.x * 256 + threadIdx.x;
    if (i < DA * DIN)            Wch[i] = (_Float16)Wc[i];
    else if (i < 2 * DA * DIN)   Wqh[i - DA * DIN] = (_Float16)Wq[i - DA * DIN];
    else                         Qh[i - 2 * DA * DIN] = (_Float16)q[i - 2 * DA * DIN];
}

// ---------------- K0b: qp'[lb][n] = query@Wq^T + bq + bc -------------------
__global__ __launch_bounds__(256) void qp_gemm(
    const _Float16* __restrict__ Qh,    // [LB][DIN]
    const _Float16* __restrict__ Wqh,   // [DA][DIN]
    const float* __restrict__ bq, const float* __restrict__ bc,
    float* __restrict__ qp)             // [LB][DA]
{
    __shared__ __align__(16) _Float16 lA[64 * 64];
    __shared__ __align__(16) _Float16 lB[64 * 64];
    const int t = threadIdx.x;
    const int w = t >> 6, lane = t & 63;
    const int quad = lane >> 4, m16 = lane & 15;
    const int n0 = blockIdx.x * 64, lb0 = blockIdx.y * 64;

    f32x4 acc[4] = {};

    for (int kt = 0; kt < DIN / 64; ++kt) {
#pragma unroll
        for (int i = 0; i < 2; ++i) {
            int c = (w * 2 + i) * 64 + lane;
            int row = c >> 3;
            int kc = (c & 7) ^ (row & 7);
            load_lds16(Qh  + (size_t)(lb0 + row) * DIN + kt * 64 + kc * 8, (char*)lA + (size_t)c * 16);
            load_lds16(Wqh + (size_t)(n0  + row) * DIN + kt * 64 + kc * 8, (char*)lB + (size_t)c * 16);
        }
        __syncthreads();
#pragma unroll
        for (int kk = 0; kk < 64; kk += 32) {
            int cq = (kk >> 3) + quad;
            int ar = 16 * w + m16;
            f16x8 a = *(const f16x8*)((const char*)lA + ar * 128 + ((cq ^ (ar & 7)) * 16));
#pragma unroll
            for (int j = 0; j < 4; ++j) {
                int br = 16 * j + m16;
                f16x8 b = *(const f16x8*)((const char*)lB + br * 128 + ((cq ^ (br & 7)) * 16));
                acc[j] = __builtin_amdgcn_mfma_f32_16x16x32_f16(a, b, acc[j], 0, 0, 0);
            }
        }
        __syncthreads();
    }
#pragma unroll
    for (int j = 0; j < 4; ++j) {
        int n = n0 + 16 * j + m16;
        float bias = bq[n] + bc[n];
#pragma unroll
        for (int r = 0; r < 4; ++r) {
            int lb = lb0 + 16 * w + quad * 4 + r;
            qp[(size_t)lb * DA + n] = acc[j][r] + bias;
        }
    }
}

// ---------------- K1: fused cvt + score GEMM (BM=128, BN=512=all N) --------
// Reads fp32 ctx ONCE, writes fp16 ctxh (for weighted_sum), computes full
// score rows (no partials, no atomics). qp folded into MFMA C-init.
__global__ __launch_bounds__(512, 2) void score_gemm4(
    const float* __restrict__ ctx,      // [M_TOT][DIN] fp32
    const _Float16* __restrict__ Wch,   // [DA][DIN] fp16 (L2-resident)
    const float* __restrict__ qp,       // [LB][DA]
    const float* __restrict__ v,        // [DA]
    _Float16* __restrict__ ctxh,        // [M_TOT][DIN] fp16 out
    float* __restrict__ sc)             // [M_TOT] final scores
{
    __shared__ __align__(16) _Float16 lA[BM * BK];          // 16 KB (single)
    __shared__ __align__(16) _Float16 lB[2][BN * BK];       // 128 KB (double)
    __shared__ float lP[4][BM];                             // 2 KB

    const int t = threadIdx.x;
    const int w = t >> 6, lane = t & 63;
    const int quad = lane >> 4, m16 = lane & 15;
    const int wm = w & 1, wn = w >> 1;          // 2 M-halves x 4 N-quarters

    // XCD-aware bijective swizzle (512 blocks, 512 % 8 == 0)
    int bid = blockIdx.x;
    int mb = (bid & 7) * 64 + (bid >> 3);
    const int m0 = mb * BM;
    const int lb0 = m0 & (LB - 1);

    // ---- A staging geometry: 128 rows x 64 cols fp32, 512 threads ----
    const int arow = t >> 2;              // 0..127
    const int c0   = (t & 3) * 2;         // chunk pair {c0, c0+1} of 8

    // ---- B staging: 512 rows x 64 cols f16 = 4096 chunks, 8/thread ----
    auto stageB = [&](int kt, int buf) {
#pragma unroll
        for (int i = 0; i < 8; ++i) {
            int c = (w * 8 + i) * 64 + lane;      // 0..4095
            int row = c >> 3;                     // 0..511
            int kc = (c & 7) ^ (row & 7);
            load_lds16(Wch + (size_t)row * DIN + kt * BK + kc * 8,
                       (char*)lB[buf] + (size_t)c * 16);
        }
    };

    f32x4 pf[4];
    auto issueA = [&](int kt) {
        const float* p = ctx + (size_t)(m0 + arow) * DIN + kt * BK + c0 * 8;
        pf[0] = *(const f32x4*)(p);
        pf[1] = *(const f32x4*)(p + 4);
        pf[2] = *(const f32x4*)(p + 8);
        pf[3] = *(const f32x4*)(p + 12);
    };

    // prologue: issue tile 0 staging, overlap qp C-init under it
    stageB(0, 0);
    issueA(0);

    f32x4 acc[4][8];
#pragma unroll
    for (int i = 0; i < 4; ++i) {
        int rl = lb0 + wm * 64 + 16 * i + quad * 4;
#pragma unroll
        for (int j = 0; j < 8; ++j) {
            int n = wn * 128 + 16 * j + m16;
#pragma unroll
            for (int r = 0; r < 4; ++r)
                acc[i][j][r] = qp[(size_t)(rl + r) * DA + n];
        }
    }

    asm volatile("s_waitcnt vmcnt(0)" ::: "memory");
    __builtin_amdgcn_s_barrier();
    __builtin_amdgcn_sched_barrier(0);

    for (int kt = 0; kt < NT; ++kt) {
        const int cur = kt & 1;

        // convert the prefetched fp32 A chunk -> f16, LDS (swizzled) + global ctxh
        f16x8 h0 = {(_Float16)pf[0][0], (_Float16)pf[0][1], (_Float16)pf[0][2], (_Float16)pf[0][3],
                    (_Float16)pf[1][0], (_Float16)pf[1][1], (_Float16)pf[1][2], (_Float16)pf[1][3]};
        f16x8 h1 = {(_Float16)pf[2][0], (_Float16)pf[2][1], (_Float16)pf[2][2], (_Float16)pf[2][3],
                    (_Float16)pf[3][0], (_Float16)pf[3][1], (_Float16)pf[3][2], (_Float16)pf[3][3]};
        *(f16x8*)((char*)lA + arow * 128 + (((c0)     ^ (arow & 7)) * 16)) = h0;
        *(f16x8*)((char*)lA + arow * 128 + (((c0 + 1) ^ (arow & 7)) * 16)) = h1;
        _Float16* cd = ctxh + (size_t)(m0 + arow) * DIN + kt * BK + c0 * 8;
        *(f16x8*)cd = h0;
        *(f16x8*)(cd + 8) = h1;

        // prefetch next tile (stays in flight across compute)
        if (kt + 1 < NT) { stageB(kt + 1, cur ^ 1); issueA(kt + 1); }

        asm volatile("s_waitcnt lgkmcnt(0)" ::: "memory");   // own ds_writes done
        __builtin_amdgcn_s_barrier();                         // lA(kt), lB[cur](kt) ready
        __builtin_amdgcn_sched_barrier(0);

#pragma unroll
        for (int kk2 = 0; kk2 < 2; ++kk2) {
            int cq = kk2 * 4 + quad;
            f16x8 a[4], b[8];
#pragma unroll
            for (int i = 0; i < 4; ++i) {
                int ar = wm * 64 + 16 * i + m16;
                a[i] = *(const f16x8*)((const char*)lA + ar * 128 + ((cq ^ (ar & 7)) * 16));
            }
#pragma unroll
            for (int j = 0; j < 8; ++j) {
                int br = wn * 128 + 16 * j + m16;
                b[j] = *(const f16x8*)((const char*)lB[cur] + br * 128 + ((cq ^ (br & 7)) * 16));
            }
            __builtin_amdgcn_s_setprio(1);
#pragma unroll
            for (int i = 0; i < 4; ++i)
#pragma unroll
                for (int j = 0; j < 8; ++j)
                    acc[i][j] = __builtin_amdgcn_mfma_f32_16x16x32_f16(a[i], b[j], acc[i][j], 0, 0, 0);
            __builtin_amdgcn_s_setprio(0);
        }

        asm volatile("s_waitcnt vmcnt(0)" ::: "memory");  // next tile + ctxh stores landed
        __builtin_amdgcn_s_barrier();
        __builtin_amdgcn_sched_barrier(0);
    }

    // epilogue: tanh + v-dot (qp already folded into acc)
    float vv[8];
#pragma unroll
    for (int j = 0; j < 8; ++j) vv[j] = v[wn * 128 + 16 * j + m16];

    float part[16];
#pragma unroll
    for (int i = 0; i < 4; ++i)
#pragma unroll
        for (int r = 0; r < 4; ++r) {
            float s = 0.f;
#pragma unroll
            for (int j = 0; j < 8; ++j)
                s += fast_tanh(acc[i][j][r]) * vv[j];
            part[i * 4 + r] = s;
        }
#pragma unroll
    for (int off = 1; off < 16; off <<= 1) {
#pragma unroll
        for (int k = 0; k < 16; ++k) part[k] += __shfl_xor(part[k], off, 64);
    }
    if (m16 == 0) {
#pragma unroll
        for (int k = 0; k < 16; ++k) {
            int rl = wm * 64 + 16 * (k >> 2) + quad * 4 + (k & 3);
            lP[wn][rl] = part[k];
        }
    }
    __syncthreads();
    if (t < BM) {
        float s = lP[0][t] + lP[1][t] + lP[2][t] + lP[3][t];
        sc[m0 + t] = s;
    }
}

// ---------------- K1-B fallback: fp32-ctx score GEMM (atomic path) ---------
__global__ __launch_bounds__(256, 3) void score_gemm(
    const float* __restrict__ ctx, const _Float16* __restrict__ Wch,
    const float* __restrict__ qp, const float* __restrict__ v,
    float* __restrict__ scores)
{
    __shared__ __align__(16) _Float16 lA[128 * 64];
    __shared__ __align__(16) _Float16 lB[128 * 64];
    __shared__ float lP[2][128];

    const int t = threadIdx.x;
    const int w = t >> 6, lane = t & 63;
    const int quad = lane >> 4, m16 = lane & 15;
    const int wm = w & 1, wn = w >> 1;

    int bid = blockIdx.x;
    int xcd = bid & 7;
    int j2 = bid >> 3;
    int nqf = j2 & 3;
    int mbf = ((j2 >> 2) << 3) | xcd;
    const int m0 = mbf * 128;
    const int n0 = nqf * 128;

    f32x4 acc[4][4] = {};

    const int arow = t >> 1;
    const int akc4 = (t & 1) * 4;
    const float* gA = ctx + (size_t)(m0 + arow) * DIN + (t & 1) * 32;

    for (int kt = 0; kt < DIN / 64; ++kt) {
        {
            const float* p = gA + kt * 64;
            f32x4 f[8];
#pragma unroll
            for (int qd = 0; qd < 8; ++qd) f[qd] = *(const f32x4*)(p + qd * 4);
#pragma unroll
            for (int q2 = 0; q2 < 4; ++q2) {
                f16x8 h = {(_Float16)f[2*q2][0], (_Float16)f[2*q2][1],
                           (_Float16)f[2*q2][2], (_Float16)f[2*q2][3],
                           (_Float16)f[2*q2+1][0], (_Float16)f[2*q2+1][1],
                           (_Float16)f[2*q2+1][2], (_Float16)f[2*q2+1][3]};
                int c = akc4 + q2;
                *(f16x8*)((char*)lA + arow * 128 + ((c ^ (arow & 7)) * 16)) = h;
            }
        }
#pragma unroll
        for (int i = 0; i < 4; ++i) {
            int c = (w * 4 + i) * 64 + lane;
            int row = c >> 3;
            int kc = (c & 7) ^ (row & 7);
            load_lds16(Wch + (size_t)(n0 + row) * DIN + kt * 64 + kc * 8, (char*)lB + (size_t)c * 16);
        }
        __syncthreads();
#pragma unroll
        for (int kk = 0; kk < 64; kk += 32) {
            int cq = (kk >> 3) + quad;
            f16x8 a[4], b[4];
#pragma unroll
            for (int i = 0; i < 4; ++i) {
                int ar = wm * 64 + 16 * i + m16;
                a[i] = *(const f16x8*)((const char*)lA + ar * 128 + ((cq ^ (ar & 7)) * 16));
            }
#pragma unroll
            for (int j = 0; j < 4; ++j) {
                int br = wn * 64 + 16 * j + m16;
                b[j] = *(const f16x8*)((const char*)lB + br * 128 + ((cq ^ (br & 7)) * 16));
            }
#pragma unroll
            for (int i = 0; i < 4; ++i)
#pragma unroll
                for (int j = 0; j < 4; ++j)
                    acc[i][j] = __builtin_amdgcn_mfma_f32_16x16x32_f16(a[i], b[j], acc[i][j], 0, 0, 0);
        }
        __syncthreads();
    }

    float vv[4];
    int nn[4];
#pragma unroll
    for (int j = 0; j < 4; ++j) { nn[j] = n0 + wn * 64 + 16 * j + m16; vv[j] = v[nn[j]]; }

    float part[16];
#pragma unroll
    for (int i = 0; i < 4; ++i) {
#pragma unroll
        for (int r = 0; r < 4; ++r) {
            int gm = m0 + wm * 64 + 16 * i + quad * 4 + r;
            int lb = gm & (LB - 1);
            float s = 0.f;
#pragma unroll
            for (int j = 0; j < 4; ++j) {
                float x = acc[i][j][r] + qp[(size_t)lb * DA + nn[j]];
                s += fast_tanh(x) * vv[j];
            }
            part[i * 4 + r] = s;
        }
    }
#pragma unroll
    for (int off = 1; off < 16; off <<= 1) {
#pragma unroll
        for (int k = 0; k < 16; ++k) part[k] += __shfl_xor(part[k], off, 64);
    }
    if (m16 == 0) {
#pragma unroll
        for (int k = 0; k < 16; ++k) {
            int row_local = wm * 64 + 16 * (k >> 2) + quad * 4 + (k & 3);
            lP[wn][row_local] = part[k];
        }
    }
    __syncthreads();
    if (t < 128) {
        float s = lP[0][t] + lP[1][t];
        atomicAdd(&scores[m0 + t], s);
    }
}

// ---------------- K2: softmax over s — one wave per lb ---------------------
__global__ __launch_bounds__(64) void softmax2(const float* __restrict__ scores,
                                               const int* __restrict__ mask,
                                               float* __restrict__ alpha) {
    int lb = blockIdx.x;
    int s = threadIdx.x;
    float x = scores[s * LB + lb];
    if (mask[s * LB + lb] == 0) x = -1e9f;
    float mx = x;
#pragma unroll
    for (int off = 1; off < 64; off <<= 1) mx = fmaxf(mx, __shfl_xor(mx, off, 64));
    float e = __expf(x - mx);
    float sum = e;
#pragma unroll
    for (int off = 1; off < 64; off <<= 1) sum += __shfl_xor(sum, off, 64);
    alpha[s * LB + lb] = e / sum;
}

// ---------------- K3-A: weighted sum from fp16 ctx_h -----------------------
__global__ __launch_bounds__(128) void weighted_sum2(
    const _Float16* __restrict__ ctxh, const float* __restrict__ alpha,
    float* __restrict__ out) {
    __shared__ float lAl[S_DIM];
    const int lb = blockIdx.x;
    const int t = threadIdx.x;
    if (t < S_DIM) lAl[t] = alpha[t * LB + lb];
    __syncthreads();
    float acc[8] = {};
    const _Float16* base = ctxh + (size_t)lb * DIN + t * 8;
#pragma unroll 8
    for (int s = 0; s < S_DIM; ++s) {
        float a = lAl[s];
        f16x8 c = *(const f16x8*)(base + (size_t)s * LB * DIN);
#pragma unroll
        for (int j = 0; j < 8; ++j) acc[j] += a * (float)c[j];
    }
    f32x4 lo = {acc[0], acc[1], acc[2], acc[3]};
    f32x4 hi = {acc[4], acc[5], acc[6], acc[7]};
    *(f32x4*)(out + (size_t)lb * DIN + t * 8) = lo;
    *(f32x4*)(out + (size_t)lb * DIN + t * 8 + 4) = hi;
}

// ---------------- K3-B fallback: weighted sum from fp32 ctx ----------------
__global__ __launch_bounds__(256) void weighted_sum(
    const float* __restrict__ ctx, const float* __restrict__ alpha,
    float* __restrict__ out) {
    __shared__ float lAl[S_DIM];
    const int lb = blockIdx.x;
    const int t = threadIdx.x;
    if (t < S_DIM) lAl[t] = alpha[t * LB + lb];
    __syncthreads();
    f32x4 acc = {0.f, 0.f, 0.f, 0.f};
    const float* base = ctx + (size_t)lb * DIN + t * 4;
#pragma unroll 4
    for (int s = 0; s < S_DIM; ++s) {
        float a = lAl[s];
        f32x4 c = *(const f32x4*)(base + (size_t)s * LB * DIN);
        acc += a * c;
    }
    *(f32x4*)(out + (size_t)lb * DIN + t * 4) = acc;
}

extern "C" void kernel_launch(void* const* d_in, const int* in_sizes, int n_in,
                              void* d_out, int out_size, void* d_ws, size_t ws_size,
                              hipStream_t stream) {
    (void)in_sizes; (void)n_in; (void)out_size;
    const float* ctx   = (const float*)d_in[0];
    const float* query = (const float*)d_in[1];
    const int*   mask  = (const int*)d_in[2];
    const float* Wc    = (const float*)d_in[3];
    const float* bc    = (const float*)d_in[4];
    const float* Wq    = (const float*)d_in[5];
    const float* bq    = (const float*)d_in[6];
    const float* v     = (const float*)d_in[7];

    float* out_attn  = (float*)d_out;                       // [LB][DIN]
    float* out_alpha = (float*)d_out + (size_t)LB * DIN;    // [S][LB]

    char* ws = (char*)d_ws;
    _Float16* Wch = (_Float16*)(ws);                        // 1 MB
    _Float16* Wqh = (_Float16*)(ws + (1 << 20));            // 1 MB
    _Float16* Qh  = (_Float16*)(ws + (2 << 20));            // 2 MB
    float*    qp  = (float*)(ws + (4 << 20));               // 2 MB
    float*    sc  = (float*)(ws + (6 << 20));               // 256 KB
    _Float16* ctxh = (_Float16*)(ws + (8 << 20));           // 128 MB

    const size_t need = (size_t)(8 + 128) << 20;
    const bool bigws = ws_size >= need;

    cvt_all<<<(2 * DA * DIN + LB * DIN) / 256, 256, 0, stream>>>(Wc, Wq, query, Wch, Wqh, Qh);
    qp_gemm<<<dim3(DA / 64, LB / 64), 256, 0, stream>>>(Qh, Wqh, bq, bc, qp);

    if (bigws) {
        // fused: score GEMM reads fp32 ctx once, emits ctxh + final scores
        score_gemm4<<<M_TOT / BM, 512, 0, stream>>>(ctx, Wch, qp, v, ctxh, sc);
        softmax2<<<LB, 64, 0, stream>>>(sc, mask, out_alpha);
        weighted_sum2<<<LB, 128, 0, stream>>>(ctxh, out_alpha, out_attn);
    } else {
        hipMemsetAsync(sc, 0, (size_t)M_TOT * sizeof(float), stream);
        score_gemm<<<2048, 256, 0, stream>>>(ctx, Wch, qp, v, sc);
        softmax2<<<LB, 64, 0, stream>>>(sc, mask, out_alpha);
        weighted_sum<<<LB, 256, 0, stream>>>(ctx, out_alpha, out_attn);
    }
}